// Round 1
// baseline (10545.857 us; speedup 1.0000x reference)
//
#include <hip/hip_runtime.h>

#define BB 128
#define TT 1000
#define FF 20
#define HH 256
#define OO 200

// broadcast a (known-uniform) 64-bit mask to SGPRs so the gather control flow scalarizes
__device__ __forceinline__ unsigned long long uni64(unsigned long long m) {
    unsigned int lo = (unsigned int)__builtin_amdgcn_readfirstlane((int)(m & 0xffffffffull));
    unsigned int hi = (unsigned int)__builtin_amdgcn_readfirstlane((int)(m >> 32));
    return ((unsigned long long)hi << 32) | (unsigned long long)lo;
}

// sum of base[(rowbase+i)*stride] over set bits i of m, ascending, 16 loads in flight per chunk
__device__ __forceinline__ float gather16(const float* __restrict__ base,
                                          unsigned long long m,
                                          int rowbase, int stride) {
    float s = 0.0f;
    while (m) {
        int cnt = __popcll(m);
        int idx[16];
#pragma unroll
        for (int u = 0; u < 16; ++u) {
            idx[u] = m ? (__ffsll((unsigned long long)m) - 1) : 0;
            m &= (m - 1);
        }
        float v[16];
#pragma unroll
        for (int u = 0; u < 16; ++u)
            v[u] = base[(size_t)((rowbase + idx[u]) * stride)];
        float a = 0.0f;
#pragma unroll
        for (int u = 0; u < 16; ++u)
            a += (u < cnt) ? v[u] : 0.0f;
        s += a;
    }
    return s;
}

__global__ __launch_bounds__(1024) void snn_main(
    const float* __restrict__ x,
    const float* __restrict__ W1, const float* __restrict__ b1,
    const float* __restrict__ Vrec1, const float* __restrict__ beta1,
    const float* __restrict__ b2,
    const float* __restrict__ Vrec2, const float* __restrict__ beta2,
    const float* __restrict__ W2T, const float* __restrict__ WoutT,
    const float* __restrict__ alpha_out, const float* __restrict__ beta_out,
    float* __restrict__ out)
{
    __shared__ float w1t_s[FF * HH];          // W1 transposed [f][h]
    __shared__ float xt_s[FF];                // x[b, t, :]
    __shared__ float part_s[4 * HH];          // quarter partial sums (P1 / P3-A)
    __shared__ float partB_s[4 * HH];         // P3-B partials
    __shared__ float partO_s[4 * OO];         // P5 partials
    __shared__ unsigned long long m1s_s[4];   // layer-1 spike masks
    __shared__ unsigned long long m2s_s[4];   // layer-2 spike masks

    const int tid = threadIdx.x;
    const int j   = tid & (HH - 1);
    const int q   = tid >> 8;                 // quarter 0..3 -> rows q*64..q*64+63
    const int b   = blockIdx.x;
    const float* xg = x + (size_t)b * TT * FF;

    // stage W1 transposed into LDS (coalesced global read)
    for (int idx = tid; idx < FF * HH; idx += 1024) {
        int h = idx / FF, f = idx - h * FF;
        w1t_s[f * HH + h] = W1[idx];
    }
    if (tid < FF) xt_s[tid] = xg[tid];
    if (tid < 4) { m1s_s[tid] = 0ull; m2s_s[tid] = 0ull; }

    // per-neuron state (quarter-0 threads own neuron j of both layers)
    float syn1 = 0.f, mem1 = 0.f, syn2 = 0.f, mem2 = 0.f;
    float vd1 = 0.f, vd2 = 0.f, b1r = 0.f, b2r = 0.f, beta1r = 0.f, beta2r = 0.f;
    bool spk1 = false, spk2 = false;
    if (q == 0) {
        b1r = b1[j]; beta1r = beta1[j]; vd1 = Vrec1[j * HH + j];
        b2r = b2[j]; beta2r = beta2[j]; vd2 = Vrec2[j * HH + j];
    }
    // output-layer state lives in wave 0: lane holds o = lane + 64*r
    float synO[4] = {0,0,0,0}, memO[4] = {0,0,0,0}, accO[4] = {0,0,0,0};
    float aOr[4] = {0,0,0,0}, bOr[4] = {0,0,0,0};
    bool  spkO[4] = {false,false,false,false};
    if (tid < 64) {
#pragma unroll
        for (int r = 0; r < 4; ++r) {
            int o = tid + (r << 6);
            if (o < OO) { aOr[r] = alpha_out[o]; bOr[r] = beta_out[o]; }
        }
    }
    __syncthreads();

    for (int t = 0; t < TT; ++t) {
        // ---- P1: layer-1 recurrent gather (spk1 from t-1) ----
        {
            unsigned long long m = uni64(m1s_s[q]);
            part_s[(q << 8) + j] = gather16(Vrec1 + j, m, q << 6, HH);
        }
        __syncthreads();
        // ---- P2: layer-1 neuron update (quarter 0) ----
        if (q == 0) {
            float wx = b1r;
#pragma unroll
            for (int f = 0; f < FF; ++f) wx = fmaf(xt_s[f], w1t_s[f * HH + j], wx);
            float g = part_s[j] + part_s[HH + j] + part_s[2 * HH + j] + part_s[3 * HH + j];
            float rst = 0.0f;
            if (spk1) { g -= vd1; rst = 1.0f; }   // zeroed diagonal + detached reset
            syn1 = fmaf(0.95f, syn1, wx + g);
            mem1 = fmaf(beta1r, mem1, syn1) - rst;
            spk1 = mem1 > 1.0f;
            unsigned long long bal = __ballot(spk1 ? 1 : 0);
            if ((tid & 63) == 0) m1s_s[tid >> 6] = bal;
        }
        __syncthreads();
        // ---- P3: layer-2 drive (W2T over spk1[t]) + recurrent (Vrec2 over spk2[t-1]) ----
        {
            unsigned long long mA = uni64(m1s_s[q]);
            unsigned long long mB = uni64(m2s_s[q]);
            part_s[(q << 8) + j]  = gather16(W2T + j,   mA, q << 6, HH);
            partB_s[(q << 8) + j] = gather16(Vrec2 + j, mB, q << 6, HH);
        }
        __syncthreads();
        // ---- P4: layer-2 neuron update (quarter 0) ----
        if (q == 0) {
            float gA = part_s[j] + part_s[HH + j] + part_s[2 * HH + j] + part_s[3 * HH + j];
            float gB = partB_s[j] + partB_s[HH + j] + partB_s[2 * HH + j] + partB_s[3 * HH + j];
            float rst = 0.0f;
            if (spk2) { gB -= vd2; rst = 1.0f; }
            syn2 = fmaf(0.95f, syn2, b2r + gA + gB);
            mem2 = fmaf(beta2r, mem2, syn2) - rst;
            spk2 = mem2 > 1.0f;
            unsigned long long bal = __ballot(spk2 ? 1 : 0);
            if ((tid & 63) == 0) m2s_s[tid >> 6] = bal;
        }
        __syncthreads();
        // ---- P5: readout drive gather (WoutT over spk2[t]) ----
        if (j < OO) {
            unsigned long long m = uni64(m2s_s[q]);
            partO_s[q * OO + j] = gather16(WoutT + j, m, q << 6, OO);
        }
        if (q == 3 && j < FF && (t + 1) < TT) xt_s[j] = xg[(size_t)(t + 1) * FF + j];
        __syncthreads();
        // ---- P6: output Synaptic neurons + online softmax + accumulate (wave 0 only) ----
        if (tid < 64) {
            float mmax = -3.402823466e38f;
#pragma unroll
            for (int r = 0; r < 4; ++r) {
                int o = tid + (r << 6);
                if (o < OO) {
                    float ot = partO_s[o] + partO_s[OO + o] + partO_s[2 * OO + o] + partO_s[3 * OO + o];
                    synO[r] = fmaf(aOr[r], synO[r], ot);
                    memO[r] = fmaf(bOr[r], memO[r], synO[r]) - (spkO[r] ? 1.0f : 0.0f);
                    spkO[r] = memO[r] > 1.0f;
                    mmax = fmaxf(mmax, memO[r]);
                }
            }
#pragma unroll
            for (int off = 32; off; off >>= 1) mmax = fmaxf(mmax, __shfl_xor(mmax, off, 64));
            float ex[4]; float se = 0.0f;
#pragma unroll
            for (int r = 0; r < 4; ++r) {
                int o = tid + (r << 6);
                ex[r] = (o < OO) ? expf(memO[r] - mmax) : 0.0f;
                se += ex[r];
            }
#pragma unroll
            for (int off = 32; off; off >>= 1) se += __shfl_xor(se, off, 64);
            if (t > 10) {
#pragma unroll
                for (int r = 0; r < 4; ++r) accO[r] += ex[r] / se;
            }
        }
        // no barrier needed: next writers of partO_s/red state sit behind >=4 barriers
    }

    if (tid < 64) {
#pragma unroll
        for (int r = 0; r < 4; ++r) {
            int o = tid + (r << 6);
            if (o < OO) out[(size_t)b * OO + o] = accO[r];
        }
    }
}

// one-shot prep: W2T[h][g] = W2[g][h]; WoutT[h][o] = Wout[o][h]
__global__ void prep_kernel(const float* __restrict__ W2, const float* __restrict__ Wout,
                            float* __restrict__ W2T, float* __restrict__ WoutT) {
    int idx = blockIdx.x * blockDim.x + threadIdx.x;
    if (idx < HH * HH) {
        int h = idx >> 8, g = idx & 255;
        W2T[idx] = W2[g * HH + h];
    }
    if (idx < HH * OO) {
        int h = idx / OO, o = idx - h * OO;
        WoutT[idx] = Wout[o * HH + h];
    }
}

extern "C" void kernel_launch(void* const* d_in, const int* in_sizes, int n_in,
                              void* d_out, int out_size, void* d_ws, size_t ws_size,
                              hipStream_t stream) {
    const float* x        = (const float*)d_in[0];
    const float* W1       = (const float*)d_in[1];
    const float* b1       = (const float*)d_in[2];
    const float* Vrec1    = (const float*)d_in[3];
    const float* beta1    = (const float*)d_in[4];
    const float* W2       = (const float*)d_in[5];
    const float* b2       = (const float*)d_in[6];
    const float* Vrec2    = (const float*)d_in[7];
    const float* beta2    = (const float*)d_in[8];
    const float* Wout     = (const float*)d_in[9];
    const float* alpha_o  = (const float*)d_in[10];
    const float* beta_o   = (const float*)d_in[11];

    float* W2T   = (float*)d_ws;              // 256*256 floats
    float* WoutT = W2T + HH * HH;             // 256*200 floats (total ~456 KB of ws)

    prep_kernel<<<256, 256, 0, stream>>>(W2, Wout, W2T, WoutT);
    snn_main<<<BB, 1024, 0, stream>>>(x, W1, b1, Vrec1, beta1, b2, Vrec2, beta2,
                                      W2T, WoutT, alpha_o, beta_o, (float*)d_out);
}

// Round 2
// 7244.779 us; speedup vs baseline: 1.4556x; 1.4556x over previous
//
#include <hip/hip_runtime.h>

#define TT 1000
#define FF 20
#define HH 256
#define OO 200

typedef unsigned int uint;

__device__ __forceinline__ int rfl(int v) { return __builtin_amdgcn_readfirstlane(v); }

// Uniform-mask row-gather: s = sum over rows r in (rowbase + bits(m)) of tab[r*stride + cx .. +3].
// m is wave-uniform -> mask iteration + row pointers stay on the scalar pipe; the load is
// SGPR-base + loop-invariant VGPR lane offset. Loads issued 16-deep before any use.
__device__ __forceinline__ float4 gatherU(const float* __restrict__ tab, int stride,
                                          unsigned m, int rowbase, int cx) {
    float4 s = make_float4(0.f, 0.f, 0.f, 0.f);
    while (m) {
        int cnt = rfl(__popc(m)); if (cnt > 16) cnt = 16;
        const float* rp[16];
#pragma unroll
        for (int u = 0; u < 16; ++u) {
            int bb = __ffs((int)m);
            int row = rfl(bb ? (rowbase + bb - 1) : 0);
            rp[u] = tab + (size_t)row * stride;
            m &= (m - 1u);
        }
        float4 v[16];
#pragma unroll
        for (int u = 0; u < 16; ++u) {
            float4 t = make_float4(0.f, 0.f, 0.f, 0.f);
            if (u < cnt) t = *(const float4*)(rp[u] + cx);   // cnt uniform -> scalar branch
            v[u] = t;
        }
#pragma unroll
        for (int u = 0; u < 16; ++u) {
            s.x += v[u].x; s.y += v[u].y; s.z += v[u].z; s.w += v[u].w;
        }
    }
    return s;
}

__global__ __launch_bounds__(1024) void snn_main(
    const float* __restrict__ x,
    const float* __restrict__ W1, const float* __restrict__ b1,
    const float* __restrict__ Vrec1, const float* __restrict__ beta1,
    const float* __restrict__ b2,
    const float* __restrict__ Vrec2, const float* __restrict__ beta2,
    const float* __restrict__ W2Tp, const float* __restrict__ WTp,
    const float* __restrict__ alpha_out, const float* __restrict__ beta_out,
    float* __restrict__ out)
{
    __shared__ float w1t_s[FF * HH];   // W1 transposed [f][h]
    __shared__ float wx_s[2][HH];      // precomputed b1 + W1 x_t (double-buffered by t parity)
    __shared__ float xts[2][FF];       // x[t] double buffer (parity t&1)
    __shared__ float pV1[8 * HH];      // Vrec1 partials (8 row-eighths)
    __shared__ float pV2[8 * HH];
    __shared__ float pW2[8 * HH];
    __shared__ float pO[8 * HH];       // WoutT partials (cols 0..199 used)
    __shared__ uint m1s[8], m2s[8];    // 256-bit spike masks as 8x32

    const int tid = threadIdx.x;
    const int b   = blockIdx.x;
    const float* xg = x + (size_t)b * TT * FF;

    // ---- init ----
    for (int idx = tid; idx < FF * HH; idx += 1024) {
        int h = idx / FF, f = idx - h * FF;
        w1t_s[f * HH + h] = W1[idx];
    }
    if (tid < FF) { xts[0][tid] = xg[tid]; xts[1][tid] = xg[FF + tid]; }
    if (tid < 8) { m1s[tid] = 0u; m2s[tid] = 0u; }
    for (int idx = tid; idx < 8 * HH; idx += 1024) pV1[idx] = 0.f;

    float syn1 = 0.f, mem1 = 0.f, syn2 = 0.f, mem2 = 0.f;
    float vd1 = 0.f, vd2 = 0.f, b2r = 0.f, beta1r = 0.f, beta2r = 0.f;
    bool spk1 = false, spk2 = false;
    if (tid < HH) {
        beta1r = beta1[tid]; beta2r = beta2[tid]; b2r = b2[tid];
        vd1 = Vrec1[tid * HH + tid]; vd2 = Vrec2[tid * HH + tid];
    }
    float b1r2 = 0.f;
    if (tid >= HH && tid < 2 * HH) b1r2 = b1[tid - HH];

    float synO[4] = {0,0,0,0}, memO[4] = {0,0,0,0}, accO[4] = {0,0,0,0};
    float aOr[4] = {0,0,0,0}, bOr[4] = {0,0,0,0};
    bool  spkO[4] = {false,false,false,false};
    if (tid >= 960) {
        int o0 = tid - 960;
#pragma unroll
        for (int r = 0; r < 4; ++r) {
            int o = o0 + (r << 6);
            if (o < OO) { aOr[r] = alpha_out[o]; bOr[r] = beta_out[o]; }
        }
    }
    __syncthreads();
    if (tid < HH) {   // wx for t=0 (own value read by same thread in B(0))
        float wx = b1[tid];
#pragma unroll
        for (int f = 0; f < FF; ++f) wx = fmaf(xts[0][f], w1t_s[f * HH + tid], wx);
        wx_s[0][tid] = wx;
    }
    __syncthreads();

    for (int t = 0; t < TT; ++t) {
        // ---- B: layer-1 update (threads 0..255) ----
        if (tid < HH) {
            float g1 = pV1[tid] + pV1[HH + tid] + pV1[2*HH + tid] + pV1[3*HH + tid]
                     + pV1[4*HH + tid] + pV1[5*HH + tid] + pV1[6*HH + tid] + pV1[7*HH + tid];
            float rst = 0.f;
            if (spk1) { g1 -= vd1; rst = 1.f; }
            syn1 = fmaf(0.95f, syn1, wx_s[t & 1][tid] + g1);
            mem1 = fmaf(beta1r, mem1, syn1) - rst;
            spk1 = mem1 > 1.0f;
            unsigned long long bal = __ballot(spk1 ? 1 : 0);
            if ((tid & 63) == 0) {
                int w = tid >> 6;
                m1s[2*w]   = (uint)bal;
                m1s[2*w+1] = (uint)(bal >> 32);
            }
        }
        __syncthreads();
        // ---- C: gather W2T(m1[t]) and Vrec2(m2[t-1]) ----
        if (tid < 512) {
            int e = tid >> 6, cq = tid & 63;
            unsigned m = (uint)rfl((int)m1s[e]);
            float4 s = gatherU(W2Tp, HH, m, e << 5, cq << 2);
            *(float4*)&pW2[(e << 8) + (cq << 2)] = s;
        } else {
            int tt2 = tid - 512;
            int e = tt2 >> 6, cq = tt2 & 63;
            unsigned m = (uint)rfl((int)m2s[e]);
            float4 s = gatherU(Vrec2, HH, m, e << 5, cq << 2);
            *(float4*)&pV2[(e << 8) + (cq << 2)] = s;
        }
        __syncthreads();
        // ---- D: layer-2 update (0..255) + wx for t+1 (256..511) ----
        if (tid < HH) {
            float gA = pW2[tid] + pW2[HH + tid] + pW2[2*HH + tid] + pW2[3*HH + tid]
                     + pW2[4*HH + tid] + pW2[5*HH + tid] + pW2[6*HH + tid] + pW2[7*HH + tid];
            float gB = pV2[tid] + pV2[HH + tid] + pV2[2*HH + tid] + pV2[3*HH + tid]
                     + pV2[4*HH + tid] + pV2[5*HH + tid] + pV2[6*HH + tid] + pV2[7*HH + tid];
            float rst = 0.f;
            if (spk2) { gB -= vd2; rst = 1.f; }
            syn2 = fmaf(0.95f, syn2, b2r + gA + gB);
            mem2 = fmaf(beta2r, mem2, syn2) - rst;
            spk2 = mem2 > 1.0f;
            unsigned long long bal = __ballot(spk2 ? 1 : 0);
            if ((tid & 63) == 0) {
                int w = tid >> 6;
                m2s[2*w]   = (uint)bal;
                m2s[2*w+1] = (uint)(bal >> 32);
            }
        } else if (tid < 2 * HH && (t + 1) < TT) {
            int j2 = tid - HH;
            const float* xx = xts[(t + 1) & 1];
            float wx = b1r2;
#pragma unroll
            for (int f = 0; f < FF; ++f) wx = fmaf(xx[f], w1t_s[f * HH + j2], wx);
            wx_s[(t + 1) & 1][j2] = wx;
        }
        __syncthreads();
        // ---- E: gather Wout(m2[t]) -> pO, Vrec1(m1[t]) -> pV1 (for B(t+1)), prefetch x[t+2] ----
        if (tid < 512) {
            int e = tid >> 6, cq = tid & 63;
            if (cq < 50) {
                unsigned m = (uint)rfl((int)m2s[e]);
                float4 s = gatherU(WTp, OO, m, e << 5, cq << 2);
                *(float4*)&pO[(e << 8) + (cq << 2)] = s;
            } else {
                int id = e * 14 + (cq - 50);
                if (id < FF && (t + 2) < TT) xts[t & 1][id] = xg[(size_t)(t + 2) * FF + id];
            }
        } else {
            int tt2 = tid - 512;
            int e = tt2 >> 6, cq = tt2 & 63;
            unsigned m = (uint)rfl((int)m1s[e]);
            float4 s = gatherU(Vrec1, HH, m, e << 5, cq << 2);
            *(float4*)&pV1[(e << 8) + (cq << 2)] = s;
        }
        __syncthreads();
        // ---- F: output layer (last wave; overlaps B(t+1) on waves 0..3) ----
        if (tid >= 960) {
            int o0 = tid - 960;
            float mmax = -3.402823466e38f;
#pragma unroll
            for (int r = 0; r < 4; ++r) {
                int o = o0 + (r << 6);
                if (o < OO) {
                    float ot = pO[o] + pO[HH + o] + pO[2*HH + o] + pO[3*HH + o]
                             + pO[4*HH + o] + pO[5*HH + o] + pO[6*HH + o] + pO[7*HH + o];
                    synO[r] = fmaf(aOr[r], synO[r], ot);
                    memO[r] = fmaf(bOr[r], memO[r], synO[r]) - (spkO[r] ? 1.f : 0.f);
                    spkO[r] = memO[r] > 1.0f;
                    mmax = fmaxf(mmax, memO[r]);
                }
            }
#pragma unroll
            for (int off = 32; off; off >>= 1) mmax = fmaxf(mmax, __shfl_xor(mmax, off, 64));
            float ex[4]; float se = 0.f;
#pragma unroll
            for (int r = 0; r < 4; ++r) {
                int o = o0 + (r << 6);
                ex[r] = (o < OO) ? expf(memO[r] - mmax) : 0.f;
                se += ex[r];
            }
#pragma unroll
            for (int off = 32; off; off >>= 1) se += __shfl_xor(se, off, 64);
            if (t > 10) {
#pragma unroll
                for (int r = 0; r < 4; ++r) accO[r] += ex[r] / se;
            }
        }
        // no barrier: B(t+1) deps (pV1 from E(t), wx from D(t)) are behind the E barrier
    }

    if (tid >= 960) {
        int o0 = tid - 960;
#pragma unroll
        for (int r = 0; r < 4; ++r) {
            int o = o0 + (r << 6);
            if (o < OO) out[(size_t)b * OO + o] = accO[r];
        }
    }
}

// one-shot prep: W2Tp[h][g] = W2[g][h]; WTp[h][o] = Wout[o][h]
__global__ void prep_kernel(const float* __restrict__ W2, const float* __restrict__ Wout,
                            float* __restrict__ W2Tp, float* __restrict__ WTp) {
    int idx = blockIdx.x * blockDim.x + threadIdx.x;
    if (idx < HH * HH) {
        int h = idx >> 8, g = idx & 255;
        W2Tp[idx] = W2[g * HH + h];
    }
    if (idx < HH * OO) {
        int h = idx / OO, o = idx - h * OO;
        WTp[idx] = Wout[o * HH + h];
    }
}

extern "C" void kernel_launch(void* const* d_in, const int* in_sizes, int n_in,
                              void* d_out, int out_size, void* d_ws, size_t ws_size,
                              hipStream_t stream) {
    const float* x       = (const float*)d_in[0];
    const float* W1      = (const float*)d_in[1];
    const float* b1      = (const float*)d_in[2];
    const float* Vrec1   = (const float*)d_in[3];
    const float* beta1   = (const float*)d_in[4];
    const float* W2      = (const float*)d_in[5];
    const float* b2      = (const float*)d_in[6];
    const float* Vrec2   = (const float*)d_in[7];
    const float* beta2   = (const float*)d_in[8];
    const float* Wout    = (const float*)d_in[9];
    const float* alpha_o = (const float*)d_in[10];
    const float* beta_o  = (const float*)d_in[11];

    float* W2Tp = (float*)d_ws;            // 256*256 floats
    float* WTp  = W2Tp + HH * HH;          // 256*200 floats (total ~467 KB)

    prep_kernel<<<256, 256, 0, stream>>>(W2, Wout, W2Tp, WTp);
    snn_main<<<128, 1024, 0, stream>>>(x, W1, b1, Vrec1, beta1, b2, Vrec2, beta2,
                                       W2Tp, WTp, alpha_o, beta_o, (float*)d_out);
}